// Round 16
// baseline (74.381 us; speedup 1.0000x reference)
//
#include <hip/hip_runtime.h>
#include <hip/hip_fp16.h>
#include <math.h>
#include <stdint.h>

#define FDIM 1024
#define BTOT 16384
#define EDIM 64
#define NFLD 32
#define NPANEL 4            // 4 panels of 256 cols
#define NPAIRS 10           // upper-tri panel pairs

typedef _Float16 half8 __attribute__((ext_vector_type(8)));
typedef __fp16 fp16x2 __attribute__((ext_vector_type(2)));
typedef float f32x4 __attribute__((ext_vector_type(4)));

// single-instruction f32x2 -> packed f16x2 (v_cvt_pkrtz_f16_f32)
__device__ __forceinline__ uint32_t pk2(float a, float b){
  fp16x2 h = __builtin_amdgcn_cvt_pkrtz(a, b);
  return __builtin_bit_cast(uint32_t, h);
}

__device__ __forceinline__ float fget(const float4& v, int i){
  switch (i){ case 0: return v.x; case 1: return v.y; case 2: return v.z; default: return v.w; }
}

// pair index for ti<=tj: (0,0)=0 (0,1)=1 (0,2)=2 (0,3)=3 (1,1)=4 ... (3,3)=9
__device__ __forceinline__ int pairId(int ti, int tj){
  return ti * NPANEL - (ti * (ti + 1)) / 2 + tj;
}

// LDS chunk-index map within a panel row of 256 chunks (write & read sides).
__device__ __forceinline__ int CMAP(int col){
  return ((col & 3) << 6) | ((col >> 2) ^ ((col & 3) << 1));
}

// ---------------------------------------------------------------------------
// w2_kernel: 1024 blocks, one field pair (a,b) each. In-block bucketing of
// fields, field-pair GEMM-lets with 32-row x 64-col (+4 pad) fp32 LDS tiles.
// Wp layout for the 16-wave gram: subtile = 64x64, 16 per pair:
//   Wp[(P*16 + w16)*4096 + ((mb*2+h)*64+lane)*8 + r2*4+nb]
// with w16=(li>>6)*4+(lj>>6), mb=(li>>4)&3, lane=((li>>2)&3)*16+(lj&15),
// h=(li&3)>>1, r2=li&1, nb=(lj>>4)&3. Strict-upper masking baked in.
// ---------------------------------------------------------------------------
__global__ __launch_bounds__(256) void w2_kernel(
    const float* __restrict__ vs, const int* __restrict__ fields,
    _Float16* __restrict__ Wp){
  __shared__ float Si[32][68];
  __shared__ float Sj[32][68];
  __shared__ int gI[32], gJ[32];
  __shared__ int cnt[NFLD], pos[NFLD], off[NFLD + 1];
  __shared__ int permS[FDIM];
  const int t = threadIdx.x;

  if (t < NFLD) cnt[t] = 0;
  __syncthreads();
#pragma unroll
  for (int r = 0; r < 4; ++r) atomicAdd(&cnt[fields[t + 256 * r]], 1);
  __syncthreads();
  if (t == 0){
    int s = 0;
    for (int i = 0; i < NFLD; ++i){ off[i] = s; s += cnt[i]; }
    off[NFLD] = s;
  }
  __syncthreads();
  if (t < NFLD) pos[t] = off[t];
  __syncthreads();
#pragma unroll
  for (int r = 0; r < 4; ++r){
    const int idx = t + 256 * r;
    const int p = atomicAdd(&pos[fields[idx]], 1);
    permS[p] = idx;
  }
  __syncthreads();

  const int a = blockIdx.x >> 5, b = blockIdx.x & 31;
  const int oa = off[a], na = off[a + 1] - oa;
  const int ob = off[b], nb_ = off[b + 1] - ob;
  if (na == 0 || nb_ == 0) return;
  for (int ia0 = 0; ia0 < na; ia0 += 32){
    const int nac = min(32, na - ia0);
    for (int jb0 = 0; jb0 < nb_; jb0 += 32){
      const int nbc = min(32, nb_ - jb0);
      __syncthreads();
      if (t < 32){
        gI[t] = (t < nac) ? permS[oa + ia0 + t] : 0;
        gJ[t] = (t < nbc) ? permS[ob + jb0 + t] : 0;
      }
      __syncthreads();
#pragma unroll
      for (int rep = 0; rep < 2; ++rep){
        const int lidx = rep * 256 + t;     // 0..511 = 32 rows x 16 float4
        const int r = lidx >> 4, e4 = (lidx & 15) * 4;
        if (r < nac)
          *(float4*)&Si[r][e4] = *(const float4*)(vs + ((size_t)b * FDIM + gI[r]) * EDIM + e4);
        if (r < nbc)
          *(float4*)&Sj[r][e4] = *(const float4*)(vs + ((size_t)a * FDIM + gJ[r]) * EDIM + e4);
      }
      __syncthreads();
      const int jr = t & 31;
      const int ir0 = t >> 5;               // 0..7
      for (int ko = 0; ko * 8 < nac; ++ko){
        const int ir = ko * 8 + ir0;
        if (ir < nac && jr < nbc){
          float dot = 0.f;
#pragma unroll
          for (int e4 = 0; e4 < EDIM; e4 += 4){
            const float4 x = *(const float4*)&Si[ir][e4];
            const float4 y = *(const float4*)&Sj[jr][e4];
            dot += x.x * y.x + x.y * y.y + x.z * y.z + x.w * y.w;
          }
          const int gi = gI[ir], gj = gJ[jr];
          const int pi = gi >> 8, pj = gj >> 8;
          if (pi <= pj){
            const float v = (gj > gi) ? dot : 0.f;
            const int li = gi & 255, lj = gj & 255;
            const int P  = pairId(pi, pj);
            const int w16 = ((li >> 6) << 2) | (lj >> 6);
            const int mb = (li >> 4) & 3, r_ = li & 3;
            const int lane = ((li >> 2) & 3) * 16 + (lj & 15);
            const int nbv = (lj >> 4) & 3;
            const size_t o_ = (size_t)(P * 16 + w16) * 4096
                            + (size_t)((mb * 2 + (r_ >> 1)) * 64 + lane) * 8
                            + (r_ & 1) * 4 + nbv;
            Wp[o_] = (_Float16)v;
          }
        }
      }
    }
  }
}

// ---------------------------------------------------------------------------
// gram_fx: fused transpose + linear + gram, 16 WAVES (1024 thr). 256 blocks
// (1/CU). Round-15's 8-wave version was latency-bound at 2 waves/SIMD
// (MfmaUtil 15%, VALU 19%, HBM 10% — all idle); 16 waves = 4/SIMD doubles
// latency hiding at the same 128 KB LDS. Per-wave acc shrinks to a 64x64
// subtile (acc 64 + wreg 32 VGPR -> fits the 128-VGPR/wave cap).
// Phase 1: wave wv stages oct (wv>>1) x 2 panels (wv&1), ds_writes CMAP'd
// chunks, accumulates the f32 linear dot into 2 partial slots.
// Phase 2: one barrier, then the pair loop; wave (wr,wc) owns subtile
// (wr*64, wc*64); diagonal pairs skip wr>wc waves (all-zero W). W-dot uses
// 4 independent accumulators (breaks the serial FMA chain).
// ---------------------------------------------------------------------------
__global__ __launch_bounds__(1024, 1) void gram_fx(
    const float* __restrict__ X, const float* __restrict__ w,
    const _Float16* __restrict__ Wp,
    float* __restrict__ partial, float* __restrict__ linp){
  __shared__ uint4 lds4[8192];   // [oct(8)][panel(4)][chunk(256) CMAP'd]
  const int t = threadIdx.x, wv = t >> 6, lane = t & 63;
  const int orow = lane >> 4, rl = lane & 15;
  const int wr = wv >> 2, wc = wv & 3;     // wave sub-tile (4 x 4) of 256x256

  // ---------------- phase 1: stage + linear ----------------
  {
    const int o  = wv >> 1;                // oct (8 rows)
    const int ph = wv & 1;                 // panel half: panels 2ph, 2ph+1
    const int k0 = blockIdx.x * 64 + o * 8;
    float lp[8];
#pragma unroll
    for (int r = 0; r < 8; ++r) lp[r] = 0.f;

#pragma unroll 1
    for (int pp = 0; pp < 2; ++pp){
      const int p = ph * 2 + pp;
      const int c0 = p * 256;
      float4 rv[8];
#pragma unroll
      for (int r = 0; r < 8; ++r)
        rv[r] = *(const float4*)(X + (size_t)(k0 + r) * FDIM + c0 + 4 * lane);
      const float4 w4 = *(const float4*)(w + c0 + 4 * lane);
#pragma unroll
      for (int r = 0; r < 8; ++r)
        lp[r] += rv[r].x * w4.x + rv[r].y * w4.y + rv[r].z * w4.z + rv[r].w * w4.w;

      uint4* base = lds4 + o * 1024 + p * 256;
#pragma unroll
      for (int i = 0; i < 4; ++i){
        uint4 ch;                          // chunk = 8 k's of col c0+4*lane+i
        ch.x = pk2(fget(rv[0], i), fget(rv[1], i));
        ch.y = pk2(fget(rv[2], i), fget(rv[3], i));
        ch.z = pk2(fget(rv[4], i), fget(rv[5], i));
        ch.w = pk2(fget(rv[6], i), fget(rv[7], i));
        base[(i << 6) | (lane ^ (i << 1))] = ch;   // CMAP(4*lane+i)
      }
    }

    // partial linear term (this wave's 2 panels) for its 8 rows
#pragma unroll
    for (int r = 0; r < 8; ++r){
      float v = lp[r];
#pragma unroll
      for (int off = 32; off; off >>= 1) v += __shfl_xor(v, off, 64);
      if (lane == 0) linp[(size_t)ph * BTOT + k0 + r] = v;
    }
  }

  __syncthreads();   // all waves' ds_writes visible; LDS read-only below

  // ---------------- phase 2: pair loop ----------------
  int swA[4], swB[4];
#pragma unroll
  for (int mb = 0; mb < 4; ++mb) swA[mb] = CMAP(wr * 64 + mb * 16 + rl);
#pragma unroll
  for (int nb = 0; nb < 4; ++nb) swB[nb] = CMAP(wc * 64 + nb * 16 + rl);

  float ws4[4] = {0.f, 0.f, 0.f, 0.f};    // 4 independent W-dot chains

  auto loadB = [&](int tj, half8 (&bf)[2][4]){
#pragma unroll
    for (int s = 0; s < 2; ++s)
#pragma unroll
      for (int nb = 0; nb < 4; ++nb)
        bf[s][nb] = __builtin_bit_cast(half8,
            lds4[(s * 4 + orow) * 1024 + tj * 256 + swB[nb]]);
  };

  auto body = [&](int ti, int tj, const half8 (&bf)[2][4]){
    // diagonal pairs: subtiles strictly below the diagonal have all-zero W
    if (ti == tj && wr > wc) return;

    // preload this pair/wave's Wp subtile (8 coalesced b128) BEFORE the MFMAs
    const uint4* wp = (const uint4*)(Wp + (size_t)(pairId(ti, tj) * 16 + wv) * 4096);
    half8 wreg[8];
#pragma unroll
    for (int q = 0; q < 8; ++q)
      wreg[q] = __builtin_bit_cast(half8, wp[q * 64 + lane]);

    f32x4 acc[4][4];
#pragma unroll
    for (int i = 0; i < 4; ++i)
#pragma unroll
      for (int j = 0; j < 4; ++j) acc[i][j] = {0.f, 0.f, 0.f, 0.f};
#pragma unroll
    for (int s = 0; s < 2; ++s)
#pragma unroll
      for (int mb = 0; mb < 4; ++mb){
        const half8 af = __builtin_bit_cast(half8,
            lds4[(s * 4 + orow) * 1024 + ti * 256 + swA[mb]]);
#pragma unroll
        for (int nb = 0; nb < 4; ++nb)
          acc[mb][nb] = __builtin_amdgcn_mfma_f32_16x16x32_f16(
              af, bf[s][nb], acc[mb][nb], 0, 0, 0);
      }
    // W-dot from registers, 4 parallel accumulators (by nb)
#pragma unroll
    for (int mb = 0; mb < 4; ++mb)
#pragma unroll
      for (int h = 0; h < 2; ++h){
        const half8 hv = wreg[mb * 2 + h];
#pragma unroll
        for (int r2 = 0; r2 < 2; ++r2)
#pragma unroll
          for (int nb = 0; nb < 4; ++nb)
            ws4[nb] += (float)hv[r2 * 4 + nb] * acc[mb][nb][2 * h + r2];
      }
  };

#pragma unroll 1
  for (int G = 0; G < NPANEL; ++G){
    half8 bf[2][4];
    loadB(G, bf);
#pragma unroll 1
    for (int ti = 0; ti <= G; ++ti) body(ti, G, bf);
  }

  float wsum = (ws4[0] + ws4[1]) + (ws4[2] + ws4[3]);

  // block reduce: wave-reduce, then cross-wave via LDS (reuse, post-barrier)
#pragma unroll
  for (int off = 32; off; off >>= 1) wsum += __shfl_xor(wsum, off, 64);
  __syncthreads();
  float* red = (float*)lds4;
  if (lane == 0) red[wv] = wsum;
  __syncthreads();
  if (t == 0){
    float s = 0.f;
#pragma unroll
    for (int i = 0; i < 16; ++i) s += red[i];
    partial[blockIdx.x] = s;
  }
}

// ---------------------------------------------------------------------------
// final_out: reduce 256 per-block gram partials (redundantly per block,
// L2-hot), add the 2 linear partial slots, sigmoid.
// ---------------------------------------------------------------------------
__global__ __launch_bounds__(256) void final_out(
    const float* __restrict__ partial, const float* __restrict__ linp,
    const float* __restrict__ wb, float* __restrict__ out){
  __shared__ float red[256];
  const int t = threadIdx.x;
  red[t] = partial[t];
  __syncthreads();
  for (int off = 128; off; off >>= 1){
    if (t < off) red[t] += red[t + off];
    __syncthreads();
  }
  const float stot = red[0] + wb[0];
  const int i = blockIdx.x * 256 + t;
  const float z = linp[i] + linp[BTOT + i] + stot;
  out[i] = 1.f / (1.f + expf(-z));
}

// ---------------------------------------------------------------------------
extern "C" void kernel_launch(void* const* d_in, const int* in_sizes, int n_in,
                              void* d_out, int out_size, void* d_ws,
                              size_t ws_size, hipStream_t stream) {
  const float* X      = (const float*)d_in[0];  // [B, F]
  const int* fields   = (const int*)d_in[1];    // [F]
  const float* ww     = (const float*)d_in[2];  // [1, F]
  const float* wbias  = (const float*)d_in[3];  // [1]
  const float* vs     = (const float*)d_in[4];  // [NF, F, E]
  float* out          = (float*)d_out;          // [B, 1]

  char* ws = (char*)d_ws;
  float* partial = (float*)ws;                        // 256 floats
  float* linp = (float*)(ws + (64 << 10));            // 2*16384 f32 = 128 KB
  _Float16* Wp = (_Float16*)(ws + (size_t)(4 << 20)); // 1.31 MB at 4 MB

  // every cell of partial/linp/Wp is written before read: no memset needed

  w2_kernel<<<NFLD * NFLD, 256, 0, stream>>>(vs, fields, Wp);
  gram_fx<<<256, 1024, 0, stream>>>(X, ww, Wp, partial, linp);
  final_out<<<BTOT / 256, 256, 0, stream>>>(partial, linp, wbias, out);
}

// Round 17
// 68.902 us; speedup vs baseline: 1.0795x; 1.0795x over previous
//
#include <hip/hip_runtime.h>
#include <hip/hip_fp16.h>
#include <math.h>
#include <stdint.h>

#define FDIM 1024
#define BTOT 16384
#define EDIM 64
#define NFLD 32
#define NPANEL 4            // 4 panels of 256 cols
#define NPAIRS 10           // upper-tri panel pairs

typedef _Float16 half8 __attribute__((ext_vector_type(8)));
typedef __fp16 fp16x2 __attribute__((ext_vector_type(2)));
typedef float f32x4 __attribute__((ext_vector_type(4)));

// single-instruction f32x2 -> packed f16x2 (v_cvt_pkrtz_f16_f32)
__device__ __forceinline__ uint32_t pk2(float a, float b){
  fp16x2 h = __builtin_amdgcn_cvt_pkrtz(a, b);
  return __builtin_bit_cast(uint32_t, h);
}

__device__ __forceinline__ float fget(const float4& v, int i){
  switch (i){ case 0: return v.x; case 1: return v.y; case 2: return v.z; default: return v.w; }
}

// pair index for ti<=tj: (0,0)=0 (0,1)=1 (0,2)=2 (0,3)=3 (1,1)=4 ... (3,3)=9
__device__ __forceinline__ int pairId(int ti, int tj){
  return ti * NPANEL - (ti * (ti + 1)) / 2 + tj;
}

// LDS chunk-index map within a panel row of 256 chunks (write & read sides).
__device__ __forceinline__ int CMAP(int col){
  return ((col & 3) << 6) | ((col >> 2) ^ ((col & 3) << 1));
}

// ---------------------------------------------------------------------------
// w2_kernel: 1024 blocks, one field pair (a,b) each. In-block bucketing of
// fields, field-pair GEMM-lets with 32-row x 64-col (+4 pad) fp32 LDS tiles,
// storing the gram-ready fp16 Wp layout (8 subtiles of 128x64 per pair,
// strict-upper masking baked in).
// ---------------------------------------------------------------------------
__global__ __launch_bounds__(256) void w2_kernel(
    const float* __restrict__ vs, const int* __restrict__ fields,
    _Float16* __restrict__ Wp){
  __shared__ float Si[32][68];
  __shared__ float Sj[32][68];
  __shared__ int gI[32], gJ[32];
  __shared__ int cnt[NFLD], pos[NFLD], off[NFLD + 1];
  __shared__ int permS[FDIM];
  const int t = threadIdx.x;

  if (t < NFLD) cnt[t] = 0;
  __syncthreads();
#pragma unroll
  for (int r = 0; r < 4; ++r) atomicAdd(&cnt[fields[t + 256 * r]], 1);
  __syncthreads();
  if (t == 0){
    int s = 0;
    for (int i = 0; i < NFLD; ++i){ off[i] = s; s += cnt[i]; }
    off[NFLD] = s;
  }
  __syncthreads();
  if (t < NFLD) pos[t] = off[t];
  __syncthreads();
#pragma unroll
  for (int r = 0; r < 4; ++r){
    const int idx = t + 256 * r;
    const int p = atomicAdd(&pos[fields[idx]], 1);
    permS[p] = idx;
  }
  __syncthreads();

  const int a = blockIdx.x >> 5, b = blockIdx.x & 31;
  const int oa = off[a], na = off[a + 1] - oa;
  const int ob = off[b], nb_ = off[b + 1] - ob;
  if (na == 0 || nb_ == 0) return;
  for (int ia0 = 0; ia0 < na; ia0 += 32){
    const int nac = min(32, na - ia0);
    for (int jb0 = 0; jb0 < nb_; jb0 += 32){
      const int nbc = min(32, nb_ - jb0);
      __syncthreads();
      if (t < 32){
        gI[t] = (t < nac) ? permS[oa + ia0 + t] : 0;
        gJ[t] = (t < nbc) ? permS[ob + jb0 + t] : 0;
      }
      __syncthreads();
#pragma unroll
      for (int rep = 0; rep < 2; ++rep){
        const int lidx = rep * 256 + t;     // 0..511 = 32 rows x 16 float4
        const int r = lidx >> 4, e4 = (lidx & 15) * 4;
        if (r < nac)
          *(float4*)&Si[r][e4] = *(const float4*)(vs + ((size_t)b * FDIM + gI[r]) * EDIM + e4);
        if (r < nbc)
          *(float4*)&Sj[r][e4] = *(const float4*)(vs + ((size_t)a * FDIM + gJ[r]) * EDIM + e4);
      }
      __syncthreads();
      const int jr = t & 31;
      const int ir0 = t >> 5;               // 0..7
      for (int ko = 0; ko * 8 < nac; ++ko){
        const int ir = ko * 8 + ir0;
        if (ir < nac && jr < nbc){
          float dot = 0.f;
#pragma unroll
          for (int e4 = 0; e4 < EDIM; e4 += 4){
            const float4 x = *(const float4*)&Si[ir][e4];
            const float4 y = *(const float4*)&Sj[jr][e4];
            dot += x.x * y.x + x.y * y.y + x.z * y.z + x.w * y.w;
          }
          const int gi = gI[ir], gj = gJ[jr];
          const int pi = gi >> 8, pj = gj >> 8;
          if (pi <= pj){
            const float v = (gj > gi) ? dot : 0.f;
            const int li = gi & 255, lj = gj & 255;
            const int P  = pairId(pi, pj);
            const int w8 = (li >> 7) * 4 + (lj >> 6);
            const int mb = (li >> 4) & 7, r_ = li & 3;
            const int lane = ((li >> 2) & 3) * 16 + (lj & 15);
            const int nbv = (lj >> 4) & 3;
            const size_t o_ = (size_t)(P * 8 + w8) * 8192
                            + (size_t)((mb * 2 + (r_ >> 1)) * 64 + lane) * 8
                            + (r_ & 1) * 4 + nbv;
            Wp[o_] = (_Float16)v;
          }
        }
      }
    }
  }
}

// ---------------------------------------------------------------------------
// gram_fx: fused transpose + linear + gram (round-15 structure, 8 waves).
// 256 blocks (1/CU), each owns ONE 64-row k-chunk of X.
// Phase 1 (staging): ALL 32 float4 X-loads issued up-front (rv[4][8], ~190
// VGPR live; rounds 15/16 serialized 8-load batches -> 0.8-1.2 TB/s measured;
// 4x in-flight bytes targets ~4x effective BW), then per-panel: linear-dot
// accumulate, fp16 pack, CMAP'd ds_write. Staging registers die before
// phase 2 (no spill: WRITE_SIZE must stay ~KB).
// Phase 2 (compute): one barrier, then the pair loop; wave (wr,wc) owns a
// 128x64 subtile; Wp subtile register-preloaded per body; diagonal pairs
// skip the 2 all-zero-W waves; W-dot uses 4 independent accumulator chains.
// ---------------------------------------------------------------------------
__global__ __launch_bounds__(512, 1) void gram_fx(
    const float* __restrict__ X, const float* __restrict__ w,
    const _Float16* __restrict__ Wp,
    float* __restrict__ partial, float* __restrict__ lin){
  __shared__ uint4 lds4[8192];   // [oct(8)][panel(4)][chunk(256) CMAP'd]
  const int t = threadIdx.x, wv = t >> 6, lane = t & 63;
  const int orow = lane >> 4, rl = lane & 15;
  const int wr = wv >> 2, wc = wv & 3;     // wave sub-tile (2 x 4) of 256x256
  const int k0 = blockIdx.x * 64 + wv * 8; // this wave's 8 rows (= its oct)

  // ---------------- phase 1: stage + linear ----------------
  float lp[8];
#pragma unroll
  for (int r = 0; r < 8; ++r) lp[r] = 0.f;

  // all 32 X-loads + 4 w-loads issued before any use: max loads in flight
  float4 w4[NPANEL];
#pragma unroll
  for (int p = 0; p < NPANEL; ++p)
    w4[p] = *(const float4*)(w + p * 256 + 4 * lane);

  float4 rv[NPANEL][8];
#pragma unroll
  for (int p = 0; p < NPANEL; ++p)
#pragma unroll
    for (int r = 0; r < 8; ++r)
      rv[p][r] = *(const float4*)(X + (size_t)(k0 + r) * FDIM + p * 256 + 4 * lane);

#pragma unroll
  for (int p = 0; p < NPANEL; ++p){
#pragma unroll
    for (int r = 0; r < 8; ++r)
      lp[r] += rv[p][r].x * w4[p].x + rv[p][r].y * w4[p].y
             + rv[p][r].z * w4[p].z + rv[p][r].w * w4[p].w;

    uint4* base = lds4 + wv * 1024 + p * 256;
#pragma unroll
    for (int i = 0; i < 4; ++i){
      uint4 ch;                            // chunk = 8 k's of col p*256+4*lane+i
      ch.x = pk2(fget(rv[p][0], i), fget(rv[p][1], i));
      ch.y = pk2(fget(rv[p][2], i), fget(rv[p][3], i));
      ch.z = pk2(fget(rv[p][4], i), fget(rv[p][5], i));
      ch.w = pk2(fget(rv[p][6], i), fget(rv[p][7], i));
      base[(i << 6) | (lane ^ (i << 1))] = ch;   // CMAP(4*lane+i)
    }
  }

  // exact-f32 linear term for this wave's 8 rows
#pragma unroll
  for (int r = 0; r < 8; ++r){
    float v = lp[r];
#pragma unroll
    for (int off = 32; off; off >>= 1) v += __shfl_xor(v, off, 64);
    if (lane == 0) lin[k0 + r] = v;
  }

  __syncthreads();   // all waves' ds_writes visible; LDS read-only below

  // ---------------- phase 2: pair loop ----------------
  int swA[8], swB[4];
#pragma unroll
  for (int mb = 0; mb < 8; ++mb) swA[mb] = CMAP(wr * 128 + mb * 16 + rl);
#pragma unroll
  for (int nb = 0; nb < 4; ++nb) swB[nb] = CMAP(wc * 64 + nb * 16 + rl);

  float ws4[4] = {0.f, 0.f, 0.f, 0.f};    // 4 independent W-dot chains

  auto loadB = [&](int tj, half8 (&bf)[2][4]){
#pragma unroll
    for (int s = 0; s < 2; ++s)
#pragma unroll
      for (int nb = 0; nb < 4; ++nb)
        bf[s][nb] = __builtin_bit_cast(half8,
            lds4[(s * 4 + orow) * 1024 + tj * 256 + swB[nb]]);
  };

  auto body = [&](int ti, int tj, const half8 (&bf)[2][4]){
    // diagonal pairs: this wave's whole 128x64 W-subtile is zero -> skip
    if (ti == tj && wr == 1 && wc < 2) return;

    // preload the pair/wave Wp subtile (16 coalesced b128) BEFORE the MFMAs
    const uint4* wp = (const uint4*)(Wp + (size_t)(pairId(ti, tj) * 8 + wv) * 8192);
    half8 wreg[16];
#pragma unroll
    for (int q = 0; q < 16; ++q)
      wreg[q] = __builtin_bit_cast(half8, wp[q * 64 + lane]);

    f32x4 acc[8][4];
#pragma unroll
    for (int i = 0; i < 8; ++i)
#pragma unroll
      for (int j = 0; j < 4; ++j) acc[i][j] = {0.f, 0.f, 0.f, 0.f};
#pragma unroll
    for (int s = 0; s < 2; ++s)
#pragma unroll
      for (int mb = 0; mb < 8; ++mb){
        const half8 af = __builtin_bit_cast(half8,
            lds4[(s * 4 + orow) * 1024 + ti * 256 + swA[mb]]);
#pragma unroll
        for (int nb = 0; nb < 4; ++nb)
          acc[mb][nb] = __builtin_amdgcn_mfma_f32_16x16x32_f16(
              af, bf[s][nb], acc[mb][nb], 0, 0, 0);
      }
    // W-dot from registers, 4 independent chains (by nb)
#pragma unroll
    for (int mb = 0; mb < 8; ++mb)
#pragma unroll
      for (int h = 0; h < 2; ++h){
        const half8 hv = wreg[mb * 2 + h];
#pragma unroll
        for (int r2 = 0; r2 < 2; ++r2)
#pragma unroll
          for (int nb = 0; nb < 4; ++nb)
            ws4[nb] += (float)hv[r2 * 4 + nb] * acc[mb][nb][2 * h + r2];
      }
  };

#pragma unroll 1
  for (int G = 0; G < NPANEL; ++G){
    half8 bf[2][4];
    loadB(G, bf);
#pragma unroll 1
    for (int ti = 0; ti <= G; ++ti) body(ti, G, bf);
  }

  float wsum = (ws4[0] + ws4[1]) + (ws4[2] + ws4[3]);

  // block reduce: wave-reduce, then cross-wave via LDS (reuse, post-barrier)
#pragma unroll
  for (int off = 32; off; off >>= 1) wsum += __shfl_xor(wsum, off, 64);
  __syncthreads();
  float* red = (float*)lds4;
  if (lane == 0) red[wv] = wsum;
  __syncthreads();
  if (t == 0){
    float s = 0.f;
#pragma unroll
    for (int i = 0; i < 8; ++i) s += red[i];
    partial[blockIdx.x] = s;
  }
}

// ---------------------------------------------------------------------------
// final_out: reduce 256 per-block gram partials (redundantly per block,
// L2-hot), add the complete linear value, sigmoid.
// ---------------------------------------------------------------------------
__global__ __launch_bounds__(256) void final_out(
    const float* __restrict__ partial, const float* __restrict__ lin,
    const float* __restrict__ wb, float* __restrict__ out){
  __shared__ float red[256];
  const int t = threadIdx.x;
  red[t] = partial[t];
  __syncthreads();
  for (int off = 128; off; off >>= 1){
    if (t < off) red[t] += red[t + off];
    __syncthreads();
  }
  const float stot = red[0] + wb[0];
  const int i = blockIdx.x * 256 + t;
  const float z = lin[i] + stot;
  out[i] = 1.f / (1.f + expf(-z));
}

// ---------------------------------------------------------------------------
extern "C" void kernel_launch(void* const* d_in, const int* in_sizes, int n_in,
                              void* d_out, int out_size, void* d_ws,
                              size_t ws_size, hipStream_t stream) {
  const float* X      = (const float*)d_in[0];  // [B, F]
  const int* fields   = (const int*)d_in[1];    // [F]
  const float* ww     = (const float*)d_in[2];  // [1, F]
  const float* wbias  = (const float*)d_in[3];  // [1]
  const float* vs     = (const float*)d_in[4];  // [NF, F, E]
  float* out          = (float*)d_out;          // [B, 1]

  char* ws = (char*)d_ws;
  float* partial = (float*)ws;                        // 256 floats
  float* lin = (float*)(ws + (64 << 10));             // 16384 f32 = 64 KB
  _Float16* Wp = (_Float16*)(ws + (size_t)(4 << 20)); // 1.25 MB at 4 MB

  // every cell of partial/lin/Wp is written before read: no memset needed

  w2_kernel<<<NFLD * NFLD, 256, 0, stream>>>(vs, fields, Wp);
  gram_fx<<<256, 512, 0, stream>>>(X, ww, Wp, partial, lin);
  final_out<<<BTOT / 256, 256, 0, stream>>>(partial, lin, wbias, out);
}